// Round 7
// baseline (964.833 us; speedup 1.0000x reference)
//
#include <hip/hip_runtime.h>
#include <hip/hip_bf16.h>
#include <math.h>

// PsiForesight fused pipeline for MI355X (gfx950).
// B=4, T=16, A=512, Z=512, E=64, H=8, HD=64, NF=6. Rows = B*T*A = 32768.
//
// R10: hybrid operand paths in gemm_kernel. A (HBM-streamed activations)
//      stays cooperatively staged via global_load_lds into 3 LDS buffers
//      with counted vmcnt (R9 skeleton, single barrier/step). B (weight
//      panels <=2MB, L2-hot, read by 128-1024 blocks) now loads DIRECTLY
//      global->VGPR with a 2-step register prefetch (named b0/b1 sets) —
//      the B LDS round-trip was ~half the LDS-pipe time (32 ds_read_b128
//      per block-step ~500cyc vs 78cyc MFMA) and bought nothing for
//      L2-resident data. LDS 48->24KB, conflicts halve, barrier publishes
//      only A. Per-step VMEM issue = {2 A-DMA, 4 B-loads} = 6 ->
//      steady-state wait is vmcnt(6), vmcnt(0) on the last step.

typedef __bf16 bf16x8 __attribute__((ext_vector_type(8)));
typedef float f32x4 __attribute__((ext_vector_type(4)));

#define ROWS 32768
#define ZDIM 512

__device__ __forceinline__ void gload16(const void* gptr, void* ldsptr) {
  __builtin_amdgcn_global_load_lds(
      (const __attribute__((address_space(1))) unsigned int*)gptr,
      (__attribute__((address_space(3))) unsigned int*)ldsptr, 16, 0, 0);
}

__device__ __forceinline__ float gelu_f(float x) {
  return 0.5f * x * (1.0f + erff(x * 0.70710678118654752f));
}

// ---------------- f32 -> bf16 transpose: out[C][R] = in[R][C] --------------
__global__ void transpose_f32_bf16(const float* __restrict__ in,
                                   __bf16* __restrict__ out, int R, int C) {
  __shared__ float tile[32][33];
  int c0 = blockIdx.x * 32, r0 = blockIdx.y * 32;
#pragma unroll
  for (int i = 0; i < 32; i += 8)
    tile[i + threadIdx.y][threadIdx.x] =
        in[(size_t)(r0 + i + threadIdx.y) * C + c0 + threadIdx.x];
  __syncthreads();
#pragma unroll
  for (int i = 0; i < 32; i += 8)
    out[(size_t)(c0 + i + threadIdx.y) * R + r0 + threadIdx.x] =
        (__bf16)tile[threadIdx.x][i + threadIdx.y];
}

// ---------------- f32 -> bf16 convert (n % 1024 == 0) ----------------------
__global__ void cvt_f32_bf16(const float* __restrict__ in,
                             __bf16* __restrict__ out) {
  int i = (blockIdx.x * 256 + threadIdx.x) * 4;
  float4 v = *(const float4*)(in + i);
  out[i + 0] = (__bf16)v.x;
  out[i + 1] = (__bf16)v.y;
  out[i + 2] = (__bf16)v.z;
  out[i + 3] = (__bf16)v.w;
}

// ---------------- LayerNorm rows (optionally x = a + gate*b) ----------------
template <bool GATED, bool EMIT_RAW>
__global__ __launch_bounds__(256) void ln_kernel(
    const float* __restrict__ xa, const __bf16* __restrict__ xb,
    const float* __restrict__ gate, const float* __restrict__ gamma,
    const float* __restrict__ beta, __bf16* __restrict__ out,
    __bf16* __restrict__ raw) {
  int row = blockIdx.x;
  int tid = threadIdx.x;
  int i0 = tid * 2;
  const float* ra = xa + (size_t)row * ZDIM;
  float x0 = ra[i0], x1 = ra[i0 + 1];
  if (EMIT_RAW) {
    raw[(size_t)row * ZDIM + i0] = (__bf16)x0;
    raw[(size_t)row * ZDIM + i0 + 1] = (__bf16)x1;
  }
  if (GATED) {
    float gv = gate[row];
    const __bf16* rb = xb + (size_t)row * ZDIM;
    x0 += gv * (float)rb[i0];
    x1 += gv * (float)rb[i0 + 1];
  }
  float s = x0 + x1, s2 = x0 * x0 + x1 * x1;
#pragma unroll
  for (int off = 32; off > 0; off >>= 1) {
    s += __shfl_down(s, off);
    s2 += __shfl_down(s2, off);
  }
  __shared__ float red[8];
  int wave = tid >> 6, lane = tid & 63;
  if (lane == 0) { red[wave] = s; red[4 + wave] = s2; }
  __syncthreads();
  float ts = red[0] + red[1] + red[2] + red[3];
  float ts2 = red[4] + red[5] + red[6] + red[7];
  float mean = ts * (1.0f / ZDIM);
  float var = ts2 * (1.0f / ZDIM) - mean * mean;
  float rstd = rsqrtf(var + 1e-5f);
  float y0 = (x0 - mean) * rstd * gamma[i0] + beta[i0];
  float y1 = (x1 - mean) * rstd * gamma[i0 + 1] + beta[i0 + 1];
  out[(size_t)row * ZDIM + i0] = (__bf16)y0;
  out[(size_t)row * ZDIM + i0 + 1] = (__bf16)y1;
}

// ---------------- edge features: e[bt][512] (all f32) ----------------------
__global__ void edge_kernel(const float* __restrict__ actions,
                            const float* __restrict__ W_edge,
                            const float* __restrict__ b_edge,
                            const float* __restrict__ We,
                            float* __restrict__ e) {
  int bt = blockIdx.x;   // 0..63
  int tid = threadIdx.x; // 0..63
  float dx = actions[bt * 4 + 0];
  float dy = actions[bt * 4 + 1];
  float th = actions[bt * 4 + 2];
  float feats[38];
  feats[0] = sinf(th);
  feats[1] = cosf(th);
  int idx = 2;
  float f = 3.14159265358979323846f;
#pragma unroll
  for (int k = 0; k < 6; k++) {
    feats[idx++] = sinf(f * dx);
    feats[idx++] = cosf(f * dx);
    feats[idx++] = sinf(f * dy);
    feats[idx++] = cosf(f * dy);
    feats[idx++] = sinf(f * th);
    feats[idx++] = cosf(f * th);
    f *= 2.0f;
  }
  __shared__ float hid[64];
  float h = b_edge[tid];
  for (int ff = 0; ff < 38; ff++) h += feats[ff] * W_edge[ff * 64 + tid];
  hid[tid] = h;
  __syncthreads();
#pragma unroll
  for (int i = 0; i < 8; i++) {
    int z = i * 64 + tid;
    float sacc = 0.0f;
    for (int j = 0; j < 64; j++) sacc += hid[j] * We[j * ZDIM + z];
    e[(size_t)bt * ZDIM + z] = sacc;
  }
}

// ---------------- per-d attention over j=8 heads ---------------------------
// kvc: [b*512+a][1024]; cols 0..511 = kc, 512..1023 = vc.
__global__ __launch_bounds__(256) void attn_kernel(
    const __bf16* __restrict__ q, const __bf16* __restrict__ kvc,
    const float* __restrict__ e, __bf16* __restrict__ attn_out) {
  int row = blockIdx.x * 4 + (threadIdx.x >> 6); // 0..32767 = bt*A + a
  int lane = threadIdx.x & 63;                   // = d
  int a = row & 511;
  int bt = row >> 9;
  int b = bt >> 4;
  const __bf16* qr = q + (size_t)row * ZDIM;
  const __bf16* kr = kvc + ((size_t)b * 512 + a) * 1024;
  const __bf16* vr = kr + 512;
  const float* er = e + (size_t)bt * ZDIM;
  float kv[8], vv[8], qv[8];
#pragma unroll
  for (int j = 0; j < 8; j++) {
    kv[j] = (float)kr[j * 64 + lane] + er[j * 64 + lane];
    vv[j] = (float)vr[j * 64 + lane];
  }
#pragma unroll
  for (int i = 0; i < 8; i++) qv[i] = (float)qr[i * 64 + lane];
  const float scale = 0.125f; // 1/sqrt(HD=64)
#pragma unroll
  for (int i = 0; i < 8; i++) {
    float lg[8], m = -1e30f;
#pragma unroll
    for (int j = 0; j < 8; j++) {
      lg[j] = qv[i] * kv[j] * scale;
      m = fmaxf(m, lg[j]);
    }
    float ssum = 0.0f, o = 0.0f;
#pragma unroll
    for (int j = 0; j < 8; j++) {
      float p = __expf(lg[j] - m);
      ssum += p;
      o += p * vv[j];
    }
    attn_out[(size_t)row * ZDIM + i * 64 + lane] = (__bf16)(o / ssum);
  }
}

// ---------------- gate GEMV: g = sigmoid(hg . Wg2 + bg2) -------------------
__global__ __launch_bounds__(256) void gate_kernel(
    const __bf16* __restrict__ hg, const float* __restrict__ Wg2,
    const float* __restrict__ bg2, float* __restrict__ g) {
  int row = blockIdx.x * 4 + (threadIdx.x >> 6);
  int lane = threadIdx.x & 63;
  float s = 0.0f;
#pragma unroll
  for (int i = 0; i < 8; i++) {
    int z = i * 64 + lane;
    s += (float)hg[(size_t)row * ZDIM + z] * Wg2[z];
  }
#pragma unroll
  for (int off = 32; off > 0; off >>= 1) s += __shfl_down(s, off);
  if (lane == 0) g[row] = 1.0f / (1.0f + expf(-(s + bg2[0])));
}

// ---------------- MFMA GEMM: C[M][N] = A[M][K] @ Bt[N][K]^T ----------------
// 128x128 block tile, BK=32, 4 waves (2x2 of 64x64), 16x16x32 bf16 MFMA.
// R10 loop (one barrier/step, counted vmcnt, A-in-LDS + B-direct):
//   step t: s_waitcnt vmcnt(6)  [A(t)'s 2 DMAs + B(t)'s 4 reg-loads done;
//                                A(t+1)+B(t+1) = 6 stay in flight]
//           s_barrier           [A tile t published; buf (t+2)%3 reusable
//                                — its readers consumed it at step t-1]
//           stageA(t+2 -> (t+2)%3)  [2 DMAs]
//           ds_read A-frags x4 ; MFMA x16 with b0/b1 ; loadB(t+2) x4
//   b0/b1 are statically-named 2-deep register prefetch of B fragments
//   (B panels are <=2MB weights, L2-hot — LDS staging was pure overhead).
// EPI: 0 = store, 1 = gelu(x + bias), 2 = x + bias + resid(bf16)
template <bool CONCAT, int EPI, typename OT>
__global__ __launch_bounds__(256) void gemm_kernel(
    const __bf16* __restrict__ A1, const __bf16* __restrict__ A2, int ksplit,
    int lda, const __bf16* __restrict__ Bt, const float* __restrict__ bias,
    const __bf16* __restrict__ resid, OT* __restrict__ C, int N, int K) {
  __shared__ __align__(16) __bf16 As[3][128 * 32];
  const int tid = threadIdx.x;
  const int wave = tid >> 6, lane = tid & 63;
  // Bijective XCD-chunked swizzle (all call-site grids have nwg % 8 == 0).
  const int nwg = gridDim.x * gridDim.y;
  const int bid = blockIdx.x + gridDim.x * blockIdx.y;
  const int sw = (bid & 7) * (nwg >> 3) + (bid >> 3);
  const int nN = gridDim.y; // # n-tiles
  const int m0 = (sw / nN) * 128, n0 = (sw % nN) * 128;
  const int srow = lane >> 2;      // staging row within 16-row chunk
  const int scol = (lane & 3) * 8; // staging col (elements)
  const int wm = (wave & 1) * 64, wn = (wave >> 1) * 64;
  const int fr = lane & 15, fq = lane >> 4;

  f32x4 acc[4][4] = {};

  auto stageA = [&](int buf, int kt) {
    const __bf16* Ap;
    int ka;
    if (CONCAT) {
      if (kt < ksplit) { Ap = A1; ka = kt; }
      else             { Ap = A2; ka = kt - ksplit; }
    } else { Ap = A1; ka = kt; }
#pragma unroll
    for (int c = 0; c < 2; c++) {
      int r = 32 * wave + 16 * c + srow;
      gload16(Ap + (size_t)(m0 + r) * lda + ka + scol,
              &As[buf][(32 * wave + 16 * c) * 32]);
    }
  };

  // Per-lane B fragment base: row n0+wn+fr (+16 per nt), col fq*8 (+kt).
  const __bf16* Bbase = Bt + (size_t)(n0 + wn + fr) * K + fq * 8;
  auto loadB = [&](bf16x8 b[4], int kt) {
#pragma unroll
    for (int x = 0; x < 4; x++)
      b[x] = *(const bf16x8*)(Bbase + (size_t)(x * 16) * K + kt);
  };

  const int nk = K >> 5; // >= 16 at all call sites
  bf16x8 b0[4], b1[4];
  stageA(0, 0);
  loadB(b0, 0);
  stageA(1, 32);
  loadB(b1, 32);

  int buf = 0;
  for (int t = 0; t < nk; ++t) {
    if (t + 1 < nk) asm volatile("s_waitcnt vmcnt(6)" ::: "memory");
    else            asm volatile("s_waitcnt vmcnt(0)" ::: "memory");
    __builtin_amdgcn_s_barrier(); // A tile t visible; buf (t+2)%3 reusable
    __builtin_amdgcn_sched_barrier(0); // nothing moves across the barrier

    if (t + 2 < nk) {
      int nb = buf + 2; if (nb >= 3) nb -= 3;
      stageA(nb, (t + 2) << 5); // DMA into buffer last read at step t-1
    }

    bf16x8 af[4];
#pragma unroll
    for (int x = 0; x < 4; x++)
      af[x] = *(const bf16x8*)&As[buf][(wm + x * 16 + fr) * 32 + fq * 8];

    if (t & 1) {
#pragma unroll
      for (int mt = 0; mt < 4; mt++)
#pragma unroll
        for (int nt = 0; nt < 4; nt++)
          acc[mt][nt] = __builtin_amdgcn_mfma_f32_16x16x32_bf16(
              af[mt], b1[nt], acc[mt][nt], 0, 0, 0);
      if (t + 2 < nk) loadB(b1, (t + 2) << 5); // refill after consumption
    } else {
#pragma unroll
      for (int mt = 0; mt < 4; mt++)
#pragma unroll
        for (int nt = 0; nt < 4; nt++)
          acc[mt][nt] = __builtin_amdgcn_mfma_f32_16x16x32_bf16(
              af[mt], b0[nt], acc[mt][nt], 0, 0, 0);
      if (t + 2 < nk) loadB(b0, (t + 2) << 5);
    }

    __builtin_amdgcn_sched_barrier(0); // contain this step's VMEM issues
    buf = (buf == 2) ? 0 : buf + 1;
  }

#pragma unroll
  for (int mt = 0; mt < 4; mt++) {
#pragma unroll
    for (int nt = 0; nt < 4; nt++) {
      int col = n0 + wn + nt * 16 + fr;
#pragma unroll
      for (int r = 0; r < 4; r++) {
        int row = m0 + wm + mt * 16 + fq * 4 + r;
        float v = acc[mt][nt][r];
        if (EPI == 1) { v = gelu_f(v + bias[col]); }
        else if (EPI == 2) {
          v += bias[col] + (float)resid[(size_t)row * N + col];
        }
        C[(size_t)row * N + col] = (OT)v;
      }
    }
  }
}

// ---------------------------------------------------------------------------
extern "C" void kernel_launch(void* const* d_in, const int* in_sizes, int n_in,
                              void* d_out, int out_size, void* d_ws,
                              size_t ws_size, hipStream_t stream) {
  const float* z_current = (const float*)d_in[0];
  const float* z_pred = (const float*)d_in[1];
  const float* actions = (const float*)d_in[2];
  const float* Wq = (const float*)d_in[3];
  const float* Wk = (const float*)d_in[4];
  const float* Wv = (const float*)d_in[5];
  const float* We = (const float*)d_in[6];
  const float* Wo = (const float*)d_in[7];
  const float* g_lnq = (const float*)d_in[8];
  const float* b_lnq = (const float*)d_in[9];
  const float* g_lno = (const float*)d_in[10];
  const float* b_lno = (const float*)d_in[11];
  const float* W_ff1 = (const float*)d_in[12];
  const float* b_ff1 = (const float*)d_in[13];
  const float* W_ff2 = (const float*)d_in[14];
  const float* b_ff2 = (const float*)d_in[15];
  const float* W_edge = (const float*)d_in[16];
  const float* b_edge = (const float*)d_in[17];
  const float* Wg1 = (const float*)d_in[18];
  const float* bg1 = (const float*)d_in[19];
  const float* Wg2 = (const float*)d_in[20];
  const float* bg2 = (const float*)d_in[21];

  char* ws = (char*)d_ws;
  size_t off = 0;
  auto alloc = [&](size_t bytes) {
    void* p = ws + off;
    off += (bytes + 255) & ~(size_t)255;
    return p;
  };
  __bf16* WTkv = (__bf16*)alloc(1024 * 512 * 2); // [0:512)=Wk^T, [512:1024)=Wv^T
  __bf16* WTq = (__bf16*)alloc(512 * 512 * 2);
  __bf16* WTo = (__bf16*)alloc(512 * 512 * 2);
  __bf16* WTg1 = (__bf16*)alloc(512 * 1024 * 2); // [512][1024]
  __bf16* WTf1 = (__bf16*)alloc(2048 * 512 * 2); // [2048][512]
  __bf16* WTf2 = (__bf16*)alloc(512 * 2048 * 2); // [512][2048]
  __bf16* zc_bf = (__bf16*)alloc(2048 * 512 * 2);
  __bf16* zp_bf = (__bf16*)alloc((size_t)ROWS * ZDIM * 2); // raw z_pred bf16
  __bf16* kvc = (__bf16*)alloc(2048 * 1024 * 2);           // fused k|v
  float* ebuf = (float*)alloc(64 * 512 * 4);
  float* gbuf = (float*)alloc(32768 * 4);
  // BUF_A and BUF_B deliberately contiguous: reused as one 16384x2048 h1 buf.
  __bf16* BUF_A = (__bf16*)alloc((size_t)2 * ROWS * ZDIM * 2);
  __bf16* BUF_B = BUF_A + (size_t)ROWS * ZDIM;
  __bf16* BUF_C = (__bf16*)alloc((size_t)ROWS * ZDIM * 2); // hg -> zmid
  (void)ws_size; (void)in_sizes; (void)n_in; (void)out_size;

  dim3 tb(32, 8);
  transpose_f32_bf16<<<dim3(16, 16), tb, 0, stream>>>(Wk, WTkv, 512, 512);
  transpose_f32_bf16<<<dim3(16, 16), tb, 0, stream>>>(Wv, WTkv + 512 * 512,
                                                      512, 512);
  transpose_f32_bf16<<<dim3(16, 16), tb, 0, stream>>>(Wq, WTq, 512, 512);
  transpose_f32_bf16<<<dim3(16, 16), tb, 0, stream>>>(Wo, WTo, 512, 512);
  transpose_f32_bf16<<<dim3(16, 32), tb, 0, stream>>>(Wg1, WTg1, 1024, 512);
  transpose_f32_bf16<<<dim3(64, 16), tb, 0, stream>>>(W_ff1, WTf1, 512, 2048);
  transpose_f32_bf16<<<dim3(16, 64), tb, 0, stream>>>(W_ff2, WTf2, 2048, 512);

  // z_current -> bf16 (2048*512 elems, 4/thread)
  cvt_f32_bf16<<<1024, 256, 0, stream>>>(z_current, zc_bf);
  // lnq = LN(z_pred) -> BUF_A ; raw bf16 z_pred -> zp_bf
  ln_kernel<false, true><<<ROWS, 256, 0, stream>>>(z_pred, nullptr, nullptr,
                                                   g_lnq, b_lnq, BUF_A, zp_bf);
  // e features
  edge_kernel<<<64, 64, 0, stream>>>(actions, W_edge, b_edge, We, ebuf);
  // kvc = z_current @ [Wk | Wv]  (M=2048, N=1024, K=512)
  gemm_kernel<false, 0, __bf16><<<dim3(16, 8), 256, 0, stream>>>(
      zc_bf, nullptr, 0, 512, WTkv, nullptr, nullptr, kvc, 1024, 512);
  // q = lnq @ Wq -> BUF_B
  gemm_kernel<false, 0, __bf16><<<dim3(256, 4), 256, 0, stream>>>(
      BUF_A, nullptr, 0, 512, WTq, nullptr, nullptr, BUF_B, 512, 512);
  // attention -> BUF_A
  attn_kernel<<<ROWS / 4, 256, 0, stream>>>(BUF_B, kvc, ebuf, BUF_A);
  // out = attn @ Wo -> BUF_B
  gemm_kernel<false, 0, __bf16><<<dim3(256, 4), 256, 0, stream>>>(
      BUF_A, nullptr, 0, 512, WTo, nullptr, nullptr, BUF_B, 512, 512);
  // hg = gelu([out, z_pred] @ Wg1 + bg1) -> BUF_C  (M=32768, N=512, K=1024)
  gemm_kernel<true, 1, __bf16><<<dim3(256, 4), 256, 0, stream>>>(
      BUF_B, zp_bf, 512, 512, WTg1, bg1, nullptr, BUF_C, 512, 1024);
  // g = sigmoid(hg . Wg2 + bg2)
  gate_kernel<<<ROWS / 4, 256, 0, stream>>>(BUF_C, Wg2, bg2, gbuf);
  // zmid = LN(z_pred + g*out) -> BUF_C
  ln_kernel<true, false><<<ROWS, 256, 0, stream>>>(z_pred, BUF_B, gbuf, g_lno,
                                                   b_lno, BUF_C, nullptr);
  // FFN in 2 chunks of 16384 rows; h1 (16384x2048 bf16, 67MB) = BUF_A+BUF_B
  float* outp = (float*)d_out;
  __bf16* h1 = BUF_A;
  for (int c = 0; c < 2; c++) {
    const __bf16* zmid_c = BUF_C + (size_t)c * 16384 * 512;
    gemm_kernel<false, 1, __bf16><<<dim3(128, 16), 256, 0, stream>>>(
        zmid_c, nullptr, 0, 512, WTf1, b_ff1, nullptr, h1, 2048, 512);
    gemm_kernel<false, 2, float><<<dim3(128, 4), 256, 0, stream>>>(
        h1, nullptr, 0, 2048, WTf2, b_ff2, zmid_c,
        outp + (size_t)c * 16384 * 512, 512, 2048);
  }
}

// Round 8
// 623.747 us; speedup vs baseline: 1.5468x; 1.5468x over previous
//
#include <hip/hip_runtime.h>
#include <hip/hip_bf16.h>
#include <math.h>

// PsiForesight fused pipeline for MI355X (gfx950).
// B=4, T=16, A=512, Z=512, E=64, H=8, HD=64, NF=6. Rows = B*T*A = 32768.
//
// R11 (consolidation): R6's verified GEMM loop (best measured: 629.7us
//     total; 3-buffer LDS, 2-tile prefetch, counted vmcnt(8/4/0), two
//     barriers per K-step, setprio around MFMA) restored EXACTLY, plus
//     the single isolated-positive increment from R9: bijective
//     XCD-chunked block swizzle, n-fastest within chunk (Wg1 FETCH
//     70->41MB, dur 75->72.5us in R9). R7/R8/R9-one-barrier/R10 all
//     regressed and are abandoned.

typedef __bf16 bf16x8 __attribute__((ext_vector_type(8)));
typedef float f32x4 __attribute__((ext_vector_type(4)));

#define ROWS 32768
#define ZDIM 512

__device__ __forceinline__ void gload16(const void* gptr, void* ldsptr) {
  __builtin_amdgcn_global_load_lds(
      (const __attribute__((address_space(1))) unsigned int*)gptr,
      (__attribute__((address_space(3))) unsigned int*)ldsptr, 16, 0, 0);
}

__device__ __forceinline__ float gelu_f(float x) {
  return 0.5f * x * (1.0f + erff(x * 0.70710678118654752f));
}

// ---------------- f32 -> bf16 transpose: out[C][R] = in[R][C] --------------
__global__ void transpose_f32_bf16(const float* __restrict__ in,
                                   __bf16* __restrict__ out, int R, int C) {
  __shared__ float tile[32][33];
  int c0 = blockIdx.x * 32, r0 = blockIdx.y * 32;
#pragma unroll
  for (int i = 0; i < 32; i += 8)
    tile[i + threadIdx.y][threadIdx.x] =
        in[(size_t)(r0 + i + threadIdx.y) * C + c0 + threadIdx.x];
  __syncthreads();
#pragma unroll
  for (int i = 0; i < 32; i += 8)
    out[(size_t)(c0 + i + threadIdx.y) * R + r0 + threadIdx.x] =
        (__bf16)tile[threadIdx.x][i + threadIdx.y];
}

// ---------------- f32 -> bf16 convert (n % 1024 == 0) ----------------------
__global__ void cvt_f32_bf16(const float* __restrict__ in,
                             __bf16* __restrict__ out) {
  int i = (blockIdx.x * 256 + threadIdx.x) * 4;
  float4 v = *(const float4*)(in + i);
  out[i + 0] = (__bf16)v.x;
  out[i + 1] = (__bf16)v.y;
  out[i + 2] = (__bf16)v.z;
  out[i + 3] = (__bf16)v.w;
}

// ---------------- LayerNorm rows (optionally x = a + gate*b) ----------------
template <bool GATED, bool EMIT_RAW>
__global__ __launch_bounds__(256) void ln_kernel(
    const float* __restrict__ xa, const __bf16* __restrict__ xb,
    const float* __restrict__ gate, const float* __restrict__ gamma,
    const float* __restrict__ beta, __bf16* __restrict__ out,
    __bf16* __restrict__ raw) {
  int row = blockIdx.x;
  int tid = threadIdx.x;
  int i0 = tid * 2;
  const float* ra = xa + (size_t)row * ZDIM;
  float x0 = ra[i0], x1 = ra[i0 + 1];
  if (EMIT_RAW) {
    raw[(size_t)row * ZDIM + i0] = (__bf16)x0;
    raw[(size_t)row * ZDIM + i0 + 1] = (__bf16)x1;
  }
  if (GATED) {
    float gv = gate[row];
    const __bf16* rb = xb + (size_t)row * ZDIM;
    x0 += gv * (float)rb[i0];
    x1 += gv * (float)rb[i0 + 1];
  }
  float s = x0 + x1, s2 = x0 * x0 + x1 * x1;
#pragma unroll
  for (int off = 32; off > 0; off >>= 1) {
    s += __shfl_down(s, off);
    s2 += __shfl_down(s2, off);
  }
  __shared__ float red[8];
  int wave = tid >> 6, lane = tid & 63;
  if (lane == 0) { red[wave] = s; red[4 + wave] = s2; }
  __syncthreads();
  float ts = red[0] + red[1] + red[2] + red[3];
  float ts2 = red[4] + red[5] + red[6] + red[7];
  float mean = ts * (1.0f / ZDIM);
  float var = ts2 * (1.0f / ZDIM) - mean * mean;
  float rstd = rsqrtf(var + 1e-5f);
  float y0 = (x0 - mean) * rstd * gamma[i0] + beta[i0];
  float y1 = (x1 - mean) * rstd * gamma[i0 + 1] + beta[i0 + 1];
  out[(size_t)row * ZDIM + i0] = (__bf16)y0;
  out[(size_t)row * ZDIM + i0 + 1] = (__bf16)y1;
}

// ---------------- edge features: e[bt][512] (all f32) ----------------------
__global__ void edge_kernel(const float* __restrict__ actions,
                            const float* __restrict__ W_edge,
                            const float* __restrict__ b_edge,
                            const float* __restrict__ We,
                            float* __restrict__ e) {
  int bt = blockIdx.x;   // 0..63
  int tid = threadIdx.x; // 0..63
  float dx = actions[bt * 4 + 0];
  float dy = actions[bt * 4 + 1];
  float th = actions[bt * 4 + 2];
  float feats[38];
  feats[0] = sinf(th);
  feats[1] = cosf(th);
  int idx = 2;
  float f = 3.14159265358979323846f;
#pragma unroll
  for (int k = 0; k < 6; k++) {
    feats[idx++] = sinf(f * dx);
    feats[idx++] = cosf(f * dx);
    feats[idx++] = sinf(f * dy);
    feats[idx++] = cosf(f * dy);
    feats[idx++] = sinf(f * th);
    feats[idx++] = cosf(f * th);
    f *= 2.0f;
  }
  __shared__ float hid[64];
  float h = b_edge[tid];
  for (int ff = 0; ff < 38; ff++) h += feats[ff] * W_edge[ff * 64 + tid];
  hid[tid] = h;
  __syncthreads();
#pragma unroll
  for (int i = 0; i < 8; i++) {
    int z = i * 64 + tid;
    float sacc = 0.0f;
    for (int j = 0; j < 64; j++) sacc += hid[j] * We[j * ZDIM + z];
    e[(size_t)bt * ZDIM + z] = sacc;
  }
}

// ---------------- per-d attention over j=8 heads ---------------------------
// kvc: [b*512+a][1024]; cols 0..511 = kc, 512..1023 = vc.
__global__ __launch_bounds__(256) void attn_kernel(
    const __bf16* __restrict__ q, const __bf16* __restrict__ kvc,
    const float* __restrict__ e, __bf16* __restrict__ attn_out) {
  int row = blockIdx.x * 4 + (threadIdx.x >> 6); // 0..32767 = bt*A + a
  int lane = threadIdx.x & 63;                   // = d
  int a = row & 511;
  int bt = row >> 9;
  int b = bt >> 4;
  const __bf16* qr = q + (size_t)row * ZDIM;
  const __bf16* kr = kvc + ((size_t)b * 512 + a) * 1024;
  const __bf16* vr = kr + 512;
  const float* er = e + (size_t)bt * ZDIM;
  float kv[8], vv[8], qv[8];
#pragma unroll
  for (int j = 0; j < 8; j++) {
    kv[j] = (float)kr[j * 64 + lane] + er[j * 64 + lane];
    vv[j] = (float)vr[j * 64 + lane];
  }
#pragma unroll
  for (int i = 0; i < 8; i++) qv[i] = (float)qr[i * 64 + lane];
  const float scale = 0.125f; // 1/sqrt(HD=64)
#pragma unroll
  for (int i = 0; i < 8; i++) {
    float lg[8], m = -1e30f;
#pragma unroll
    for (int j = 0; j < 8; j++) {
      lg[j] = qv[i] * kv[j] * scale;
      m = fmaxf(m, lg[j]);
    }
    float ssum = 0.0f, o = 0.0f;
#pragma unroll
    for (int j = 0; j < 8; j++) {
      float p = __expf(lg[j] - m);
      ssum += p;
      o += p * vv[j];
    }
    attn_out[(size_t)row * ZDIM + i * 64 + lane] = (__bf16)(o / ssum);
  }
}

// ---------------- gate GEMV: g = sigmoid(hg . Wg2 + bg2) -------------------
__global__ __launch_bounds__(256) void gate_kernel(
    const __bf16* __restrict__ hg, const float* __restrict__ Wg2,
    const float* __restrict__ bg2, float* __restrict__ g) {
  int row = blockIdx.x * 4 + (threadIdx.x >> 6);
  int lane = threadIdx.x & 63;
  float s = 0.0f;
#pragma unroll
  for (int i = 0; i < 8; i++) {
    int z = i * 64 + lane;
    s += (float)hg[(size_t)row * ZDIM + z] * Wg2[z];
  }
#pragma unroll
  for (int off = 32; off > 0; off >>= 1) s += __shfl_down(s, off);
  if (lane == 0) g[row] = 1.0f / (1.0f + expf(-(s + bg2[0])));
}

// ---------------- MFMA GEMM: C[M][N] = A[M][K] @ Bt[N][K]^T ----------------
// 128x128 block tile, BK=32, 4 waves (2x2 of 64x64), 16x16x32 bf16 MFMA.
// R6-verified loop: triple-buffered LDS, 2-tile-deep prefetch, counted
// vmcnt. Per step t:
//   wait vmcnt(8/4/0) [tile t's own 4 DMAs done; deeper prefetch in
//   flight] -> s_barrier (tile t published) -> ds_read frags ->
//   lgkmcnt(0) -> s_barrier (all reads retired => buf free) ->
//   stage(t+3 -> freed buf) -> setprio(1) MFMA x16 setprio(0).
// R11 adds the bijective XCD-chunked block swizzle (XCD = bid&7,
// n-fastest within chunk: blocks sharing an A panel run consecutively
// on the SAME XCD -> A fetched ~once per XCD, L2 reuse; R9-measured
// FETCH -40% on Wg1). All call-site grids have nwg % 8 == 0.
// EPI: 0 = store, 1 = gelu(x + bias), 2 = x + bias + resid(bf16)
template <bool CONCAT, int EPI, typename OT>
__global__ __launch_bounds__(256) void gemm_kernel(
    const __bf16* __restrict__ A1, const __bf16* __restrict__ A2, int ksplit,
    int lda, const __bf16* __restrict__ Bt, const float* __restrict__ bias,
    const __bf16* __restrict__ resid, OT* __restrict__ C, int N, int K) {
  __shared__ __align__(16) __bf16 As[3][128 * 32];
  __shared__ __align__(16) __bf16 Bs[3][128 * 32];
  const int tid = threadIdx.x;
  const int wave = tid >> 6, lane = tid & 63;
  // Bijective XCD-chunked swizzle (nwg % 8 == 0 at every call site).
  const int nwg = gridDim.x * gridDim.y;
  const int bid = blockIdx.x + gridDim.x * blockIdx.y;
  const int sw = (bid & 7) * (nwg >> 3) + (bid >> 3);
  const int nN = gridDim.y; // # n-tiles
  const int m0 = (sw / nN) * 128, n0 = (sw % nN) * 128;
  const int srow = lane >> 2;      // staging row within 16-row chunk
  const int scol = (lane & 3) * 8; // staging col (elements)
  const int wm = (wave & 1) * 64, wn = (wave >> 1) * 64;
  const int fr = lane & 15, fq = lane >> 4;

  f32x4 acc[4][4] = {};

  auto stage = [&](int buf, int kt) {
    const __bf16* Ap;
    int ka;
    if (CONCAT) {
      if (kt < ksplit) { Ap = A1; ka = kt; }
      else             { Ap = A2; ka = kt - ksplit; }
    } else { Ap = A1; ka = kt; }
#pragma unroll
    for (int c = 0; c < 2; c++) {
      int r = 32 * wave + 16 * c + srow;
      gload16(Ap + (size_t)(m0 + r) * lda + ka + scol,
              &As[buf][(32 * wave + 16 * c) * 32]);
      gload16(Bt + (size_t)(n0 + r) * K + kt + scol,
              &Bs[buf][(32 * wave + 16 * c) * 32]);
    }
  };

  const int nk = K >> 5; // all call sites have nk >= 16
  stage(0, 0);
  stage(1, 32);
  stage(2, 64);
  int buf = 0;
  for (int t = 0; t < nk; ++t) {
    const int remain = nk - 1 - t;
    // Wait for tile t's 4 DMAs; keep the deeper prefetches in flight.
    if (remain >= 2)      asm volatile("s_waitcnt vmcnt(8)" ::: "memory");
    else if (remain == 1) asm volatile("s_waitcnt vmcnt(4)" ::: "memory");
    else                  asm volatile("s_waitcnt vmcnt(0)" ::: "memory");
    __builtin_amdgcn_s_barrier(); // tile t visible to every wave

    bf16x8 af[4], bfr[4];
#pragma unroll
    for (int x = 0; x < 4; x++) {
      af[x] = *(const bf16x8*)&As[buf][(wm + x * 16 + fr) * 32 + fq * 8];
      bfr[x] = *(const bf16x8*)&Bs[buf][(wn + x * 16 + fr) * 32 + fq * 8];
    }
    asm volatile("s_waitcnt lgkmcnt(0)" ::: "memory");
    __builtin_amdgcn_sched_barrier(0);
    __builtin_amdgcn_s_barrier(); // all waves' reads retired; buf reusable

    if (t + 3 < nk) stage(buf, (t + 3) << 5); // DMA into freed buffer

    __builtin_amdgcn_s_setprio(1);
#pragma unroll
    for (int mt = 0; mt < 4; mt++)
#pragma unroll
      for (int nt = 0; nt < 4; nt++)
        acc[mt][nt] = __builtin_amdgcn_mfma_f32_16x16x32_bf16(
            af[mt], bfr[nt], acc[mt][nt], 0, 0, 0);
    __builtin_amdgcn_s_setprio(0);

    buf = (buf == 2) ? 0 : buf + 1;
  }

#pragma unroll
  for (int mt = 0; mt < 4; mt++) {
#pragma unroll
    for (int nt = 0; nt < 4; nt++) {
      int col = n0 + wn + nt * 16 + fr;
#pragma unroll
      for (int r = 0; r < 4; r++) {
        int row = m0 + wm + mt * 16 + fq * 4 + r;
        float v = acc[mt][nt][r];
        if (EPI == 1) { v = gelu_f(v + bias[col]); }
        else if (EPI == 2) {
          v += bias[col] + (float)resid[(size_t)row * N + col];
        }
        C[(size_t)row * N + col] = (OT)v;
      }
    }
  }
}

// ---------------------------------------------------------------------------
extern "C" void kernel_launch(void* const* d_in, const int* in_sizes, int n_in,
                              void* d_out, int out_size, void* d_ws,
                              size_t ws_size, hipStream_t stream) {
  const float* z_current = (const float*)d_in[0];
  const float* z_pred = (const float*)d_in[1];
  const float* actions = (const float*)d_in[2];
  const float* Wq = (const float*)d_in[3];
  const float* Wk = (const float*)d_in[4];
  const float* Wv = (const float*)d_in[5];
  const float* We = (const float*)d_in[6];
  const float* Wo = (const float*)d_in[7];
  const float* g_lnq = (const float*)d_in[8];
  const float* b_lnq = (const float*)d_in[9];
  const float* g_lno = (const float*)d_in[10];
  const float* b_lno = (const float*)d_in[11];
  const float* W_ff1 = (const float*)d_in[12];
  const float* b_ff1 = (const float*)d_in[13];
  const float* W_ff2 = (const float*)d_in[14];
  const float* b_ff2 = (const float*)d_in[15];
  const float* W_edge = (const float*)d_in[16];
  const float* b_edge = (const float*)d_in[17];
  const float* Wg1 = (const float*)d_in[18];
  const float* bg1 = (const float*)d_in[19];
  const float* Wg2 = (const float*)d_in[20];
  const float* bg2 = (const float*)d_in[21];

  char* ws = (char*)d_ws;
  size_t off = 0;
  auto alloc = [&](size_t bytes) {
    void* p = ws + off;
    off += (bytes + 255) & ~(size_t)255;
    return p;
  };
  __bf16* WTkv = (__bf16*)alloc(1024 * 512 * 2); // [0:512)=Wk^T, [512:1024)=Wv^T
  __bf16* WTq = (__bf16*)alloc(512 * 512 * 2);
  __bf16* WTo = (__bf16*)alloc(512 * 512 * 2);
  __bf16* WTg1 = (__bf16*)alloc(512 * 1024 * 2); // [512][1024]
  __bf16* WTf1 = (__bf16*)alloc(2048 * 512 * 2); // [2048][512]
  __bf16* WTf2 = (__bf16*)alloc(512 * 2048 * 2); // [512][2048]
  __bf16* zc_bf = (__bf16*)alloc(2048 * 512 * 2);
  __bf16* zp_bf = (__bf16*)alloc((size_t)ROWS * ZDIM * 2); // raw z_pred bf16
  __bf16* kvc = (__bf16*)alloc(2048 * 1024 * 2);           // fused k|v
  float* ebuf = (float*)alloc(64 * 512 * 4);
  float* gbuf = (float*)alloc(32768 * 4);
  // BUF_A and BUF_B deliberately contiguous: reused as one 16384x2048 h1 buf.
  __bf16* BUF_A = (__bf16*)alloc((size_t)2 * ROWS * ZDIM * 2);
  __bf16* BUF_B = BUF_A + (size_t)ROWS * ZDIM;
  __bf16* BUF_C = (__bf16*)alloc((size_t)ROWS * ZDIM * 2); // hg -> zmid
  (void)ws_size; (void)in_sizes; (void)n_in; (void)out_size;

  dim3 tb(32, 8);
  transpose_f32_bf16<<<dim3(16, 16), tb, 0, stream>>>(Wk, WTkv, 512, 512);
  transpose_f32_bf16<<<dim3(16, 16), tb, 0, stream>>>(Wv, WTkv + 512 * 512,
                                                      512, 512);
  transpose_f32_bf16<<<dim3(16, 16), tb, 0, stream>>>(Wq, WTq, 512, 512);
  transpose_f32_bf16<<<dim3(16, 16), tb, 0, stream>>>(Wo, WTo, 512, 512);
  transpose_f32_bf16<<<dim3(16, 32), tb, 0, stream>>>(Wg1, WTg1, 1024, 512);
  transpose_f32_bf16<<<dim3(64, 16), tb, 0, stream>>>(W_ff1, WTf1, 512, 2048);
  transpose_f32_bf16<<<dim3(16, 64), tb, 0, stream>>>(W_ff2, WTf2, 2048, 512);

  // z_current -> bf16 (2048*512 elems, 4/thread)
  cvt_f32_bf16<<<1024, 256, 0, stream>>>(z_current, zc_bf);
  // lnq = LN(z_pred) -> BUF_A ; raw bf16 z_pred -> zp_bf
  ln_kernel<false, true><<<ROWS, 256, 0, stream>>>(z_pred, nullptr, nullptr,
                                                   g_lnq, b_lnq, BUF_A, zp_bf);
  // e features
  edge_kernel<<<64, 64, 0, stream>>>(actions, W_edge, b_edge, We, ebuf);
  // kvc = z_current @ [Wk | Wv]  (M=2048, N=1024, K=512)
  gemm_kernel<false, 0, __bf16><<<dim3(16, 8), 256, 0, stream>>>(
      zc_bf, nullptr, 0, 512, WTkv, nullptr, nullptr, kvc, 1024, 512);
  // q = lnq @ Wq -> BUF_B
  gemm_kernel<false, 0, __bf16><<<dim3(256, 4), 256, 0, stream>>>(
      BUF_A, nullptr, 0, 512, WTq, nullptr, nullptr, BUF_B, 512, 512);
  // attention -> BUF_A
  attn_kernel<<<ROWS / 4, 256, 0, stream>>>(BUF_B, kvc, ebuf, BUF_A);
  // out = attn @ Wo -> BUF_B
  gemm_kernel<false, 0, __bf16><<<dim3(256, 4), 256, 0, stream>>>(
      BUF_A, nullptr, 0, 512, WTo, nullptr, nullptr, BUF_B, 512, 512);
  // hg = gelu([out, z_pred] @ Wg1 + bg1) -> BUF_C  (M=32768, N=512, K=1024)
  gemm_kernel<true, 1, __bf16><<<dim3(256, 4), 256, 0, stream>>>(
      BUF_B, zp_bf, 512, 512, WTg1, bg1, nullptr, BUF_C, 512, 1024);
  // g = sigmoid(hg . Wg2 + bg2)
  gate_kernel<<<ROWS / 4, 256, 0, stream>>>(BUF_C, Wg2, bg2, gbuf);
  // zmid = LN(z_pred + g*out) -> BUF_C
  ln_kernel<true, false><<<ROWS, 256, 0, stream>>>(z_pred, BUF_B, gbuf, g_lno,
                                                   b_lno, BUF_C, nullptr);
  // FFN in 2 chunks of 16384 rows; h1 (16384x2048 bf16, 67MB) = BUF_A+BUF_B
  float* outp = (float*)d_out;
  __bf16* h1 = BUF_A;
  for (int c = 0; c < 2; c++) {
    const __bf16* zmid_c = BUF_C + (size_t)c * 16384 * 512;
    gemm_kernel<false, 1, __bf16><<<dim3(128, 16), 256, 0, stream>>>(
        zmid_c, nullptr, 0, 512, WTf1, b_ff1, nullptr, h1, 2048, 512);
    gemm_kernel<false, 2, float><<<dim3(128, 4), 256, 0, stream>>>(
        h1, nullptr, 0, 2048, WTf2, b_ff2, zmid_c,
        outp + (size_t)c * 16384 * 512, 512, 2048);
  }
}